// Round 5
// baseline (18094.917 us; speedup 1.0000x reference)
//
#include <hip/hip_runtime.h>
#include <hip/hip_bf16.h>

#define BB 256
#define TT 256
#define FF 511
#define UU 512

typedef __bf16 bf16_t;
typedef __bf16 bf16x8 __attribute__((ext_vector_type(8)));
typedef __bf16 bf16x2 __attribute__((ext_vector_type(2)));
typedef float f32x4 __attribute__((ext_vector_type(4)));

__device__ __forceinline__ float fast_sigmoid(float x) {
  return 1.f / (1.f + __expf(-x));
}
__device__ __forceinline__ float fast_tanh(float x) {
  float a = fabsf(x);
  float t = 1.f - 2.f / (__expf(2.f * a) + 1.f);  // overflow-safe
  return copysignf(t, x);
}

// ---------------------------------------------------------------------------
// Weight prep -> fragment-major packed: Wp[frag][lane][8], frag = ntile*32+ko,
// ntile = n/16 (n in [0,2048)), ko = k/32. lane: l16 = n-offset, quad*8 = k-off.
// ---------------------------------------------------------------------------
__global__ __launch_bounds__(64) void prep_weights(
    const float* __restrict__ Wx, const float* __restrict__ Wh,
    bf16_t* __restrict__ Wp) {
  int bid = blockIdx.x;  // ntile*32 + ko
  int ko = bid & 31;
  int ntile = bid >> 5;
  int lane = threadIdx.x;
  int n = ntile * 16 + (lane & 15);
  int kb = ko * 32 + (lane >> 4) * 8;
  const float* src = (kb < UU) ? Wx : Wh;
  int krel = (kb < UU) ? kb : kb - UU;
  bf16x8 v;
#pragma unroll
  for (int j = 0; j < 8; ++j) v[j] = (bf16_t)src[(long)(krel + j) * 2048 + n];
  *(bf16x8*)(Wp + (long)bid * 512 + lane * 8) = v;
}

// ---------------------------------------------------------------------------
__global__ __launch_bounds__(256) void prep_x(
    const float* __restrict__ inputs, const float* __restrict__ score,
    bf16_t* __restrict__ X) {
  int gid = blockIdx.x * 256 + threadIdx.x;
  int u = (gid & 255) * 2;
  int b = (gid >> 8) & 255;
  int t = gid >> 16;
  long ibase = (long)b * TT * FF + (long)t * FF;
  float v0 = inputs[ibase + u];
  float v1 = (u + 1 < FF) ? inputs[ibase + u + 1] : score[b];
  bf16x2 o;
  o[0] = (bf16_t)v0;
  o[1] = (bf16_t)v1;
  *(bf16x2*)(X + (long)t * BB * UU + b * UU + u) = o;
}

// Zero h ping-pong buffers and the barrier words (ws is poisoned 0xAA).
__global__ __launch_bounds__(256) void init_state(
    bf16_t* __restrict__ hb0, bf16_t* __restrict__ hb1,
    unsigned* __restrict__ syncw) {
  int idx = blockIdx.x * 256 + threadIdx.x;
  hb0[idx] = (bf16_t)0.f;
  hb1[idx] = (bf16_t)0.f;
  if (blockIdx.x == 0 && threadIdx.x < 512) syncw[threadIdx.x] = 0u;
}

__global__ __launch_bounds__(256) void mean_kernel(
    const bf16_t* __restrict__ X, bf16_t* __restrict__ xin) {
  int idx = blockIdx.x * 256 + threadIdx.x;  // b*512+u
  float acc = 0.f;
  for (int t = 0; t < TT; ++t) acc += (float)X[(long)t * BB * UU + idx];
  xin[idx] = (bf16_t)(acc * (1.0f / TT));
}

// ---------------------------------------------------------------------------
// Monotonic GROUP barrier: group = 32 consecutive blocks (one batch-row band).
// All producer->consumer edges of the recurrence are group-local, so groups
// sync independently. syncw: counter for group g at [g*32] (128B separated),
// generation word at [256 + g*32]. n = 1-based round index.
// ---------------------------------------------------------------------------
__device__ __forceinline__ void gsync(unsigned* syncw, unsigned n) {
  __syncthreads();  // s_barrier with full vm/lgkm drain (stores issued)
  if (threadIdx.x == 0) {
    const int g = blockIdx.x >> 5;
    unsigned* cnt = syncw + g * 32;
    unsigned* gen = syncw + 256 + g * 32;
    __threadfence();  // agent-scope release of our global writes
    unsigned old = __hip_atomic_fetch_add(cnt, 1u, __ATOMIC_RELAXED,
                                          __HIP_MEMORY_SCOPE_AGENT);
    if (old == n * 32u - 1u)  // last arrival of this group's round n
      __hip_atomic_store(gen, n, __ATOMIC_RELEASE, __HIP_MEMORY_SCOPE_AGENT);
    while (__hip_atomic_load(gen, __ATOMIC_ACQUIRE, __HIP_MEMORY_SCOPE_AGENT) <
           n) {
      __builtin_amdgcn_s_sleep(1);
    }
    __threadfence();  // agent-scope acquire: discard stale cached lines
  }
  __syncthreads();
}

union ShU {
  float red[4][2][4][64][4];  // [kq][rt][gate][lane][reg] = 32 KiB
  struct {
    float sc[TT];
    float ctxs[4][UU];
    float mL[4];
    float lL[4];
  } at;  // aliased; phases separated by barriers
};

// ---------------------------------------------------------------------------
// One LSTM step. Wave = K-quarter, B-fragments resident in registers (wreg),
// A (x||h) from global. K-reduce via LDS, epilogue row-split across waves,
// c carried in thread registers across all 512 steps.
// ---------------------------------------------------------------------------
__device__ __forceinline__ void lstm_sub(
    const bf16x8 (&wreg)[4][8], const float (&bia)[4], const bf16_t* xsrc,
    const bf16_t* h_in, bf16_t* h_out, bf16_t* eslot,  // enc_out + t*UU or null
    float& c0, float& c1, ShU& sh, int mg, int js) {
  const int tid = threadIdx.x;
  const int wave = tid >> 6;  // = kq
  const int lane = tid & 63;
  const int quad = lane >> 4;
  const int l16 = lane & 15;

  f32x4 acc[2][4];
#pragma unroll
  for (int rt = 0; rt < 2; ++rt)
#pragma unroll
    for (int g = 0; g < 4; ++g) acc[rt][g] = (f32x4){0.f, 0.f, 0.f, 0.f};

  const bf16_t* abase = (wave < 2) ? xsrc : h_in;
  const int koff = (wave & 1) * 256;
  const long r0 = (long)(mg * 32 + l16) * UU;
  const long r1 = (long)(mg * 32 + 16 + l16) * UU;

#pragma unroll
  for (int kol = 0; kol < 8; ++kol) {
    const int kk = koff + kol * 32 + quad * 8;
    bf16x8 a0 = *(const bf16x8*)(abase + r0 + kk);
    bf16x8 a1 = *(const bf16x8*)(abase + r1 + kk);
#pragma unroll
    for (int g = 0; g < 4; ++g) {
      acc[0][g] = __builtin_amdgcn_mfma_f32_16x16x32_bf16(a0, wreg[g][kol],
                                                          acc[0][g], 0, 0, 0);
      acc[1][g] = __builtin_amdgcn_mfma_f32_16x16x32_bf16(a1, wreg[g][kol],
                                                          acc[1][g], 0, 0, 0);
    }
  }

#pragma unroll
  for (int rt = 0; rt < 2; ++rt)
#pragma unroll
    for (int g = 0; g < 4; ++g)
      *(f32x4*)&sh.red[wave][rt][g][lane][0] = acc[rt][g];
  __syncthreads();

  // Epilogue: wave w -> rows 8*(w&1)+ro+4*cc of half rt=w>>1; col = l16.
  const int col = l16;
  const int ro = lane >> 4;
  const int rt = wave >> 1;
  const int j = js * 16 + col;
#pragma unroll
  for (int cc = 0; cc < 2; ++cc) {
    const int row16 = 8 * (wave & 1) + ro + 4 * cc;
    const int q16 = row16 >> 2;
    const int rr = row16 & 3;
    float z[4];
#pragma unroll
    for (int g = 0; g < 4; ++g) {
      z[g] = bia[g];
#pragma unroll
      for (int kq = 0; kq < 4; ++kq)
        z[g] += sh.red[kq][rt][g][q16 * 16 + col][rr];
    }
    float ig = fast_sigmoid(z[0]);
    float fg = fast_sigmoid(z[1]);
    float gg = fast_tanh(z[2]);
    float og = fast_sigmoid(z[3]);
    float& cref = cc ? c1 : c0;
    float cn = fg * cref + ig * gg;
    float hn = og * fast_tanh(cn);
    cref = cn;
    const int b = mg * 32 + rt * 16 + row16;
    h_out[(long)b * UU + j] = (bf16_t)hn;
    if (eslot) eslot[(long)b * TT * UU + j] = (bf16_t)hn;
  }
}

// ---------------------------------------------------------------------------
// Persistent kernel: 256 WGs x 256 threads, REGULAR launch. Group barriers.
// ---------------------------------------------------------------------------
__global__ __launch_bounds__(256, 1) void pointer_net_persistent(
    const bf16_t* __restrict__ Xbf, bf16_t* __restrict__ xin,
    const bf16_t* __restrict__ WencP, const bf16_t* __restrict__ WdecP,
    const float* __restrict__ enc_b, const float* __restrict__ dec_b,
    bf16_t* __restrict__ h0, bf16_t* __restrict__ h1,
    bf16_t* __restrict__ enc_out, const float* __restrict__ ptr_w,
    const float* __restrict__ ptr_b, float* __restrict__ out,
    unsigned* __restrict__ syncw) {
  __shared__ ShU sh;
  const int tid = threadIdx.x;
  const int wave = tid >> 6;
  const int lane = tid & 63;
  const int mg = blockIdx.x >> 5;  // 0..7 (batch band)
  const int js = blockIdx.x & 31;  // 0..31 (gate-col tile)
  const int b_att = blockIdx.x;    // attention batch row (same band!)

  const float pw = *ptr_w, pb = *ptr_b;

  bf16x8 wreg[4][8];
  float bia[4];
#pragma unroll
  for (int g = 0; g < 4; ++g) {
#pragma unroll
    for (int kol = 0; kol < 8; ++kol) {
      long frag = (long)(g * 32 + js) * 32 + wave * 8 + kol;
      wreg[g][kol] = *(const bf16x8*)(WencP + frag * 512 + lane * 8);
    }
    bia[g] = enc_b[g * UU + js * 16 + (lane & 15)];
  }

  float c0 = 0.f, c1 = 0.f;
  bf16_t* hp[2] = {h0, h1};
  int p = 0;
  unsigned nsync = 0;

  // -------- Encoder: 256 steps --------
  for (int t = 0; t < TT; ++t) {
    lstm_sub(wreg, bia, Xbf + (long)t * BB * UU, hp[p], hp[p ^ 1],
             enc_out + (long)t * UU, c0, c1, sh, mg, js);
    p ^= 1;
    gsync(syncw, ++nsync);
  }

  // -------- Switch to decoder weights --------
#pragma unroll
  for (int g = 0; g < 4; ++g) {
#pragma unroll
    for (int kol = 0; kol < 8; ++kol) {
      long frag = (long)(g * 32 + js) * 32 + wave * 8 + kol;
      wreg[g][kol] = *(const bf16x8*)(WdecP + frag * 512 + lane * 8);
    }
    bia[g] = dec_b[g * UU + js * 16 + (lane & 15)];
  }

  // -------- Decoder: 256 steps of (LSTM, attention) --------
  for (int s = 0; s < TT; ++s) {
    lstm_sub(wreg, bia, xin, hp[p], hp[p ^ 1], nullptr, c0, c1, sh, mg, js);
    p ^= 1;
    gsync(syncw, ++nsync);

    // ---- Attention (WG = batch row b_att), online softmax ----
    {
      const int b = b_att;
      bf16x8 hv = *(const bf16x8*)(hp[p] + (long)b * UU + lane * 8);
      float hf[8];
#pragma unroll
      for (int j = 0; j < 8; ++j) hf[j] = (float)hv[j];

      const bf16_t* eb = enc_out + (long)b * TT * UU;
      float m = -1e30f, l = 0.f;
      float ctx[8];
#pragma unroll
      for (int j = 0; j < 8; ++j) ctx[j] = 0.f;

      for (int ch = 0; ch < 8; ++ch) {
        const int tb = wave * 64 + ch * 8;
        bf16x8 er[8];
#pragma unroll
        for (int q = 0; q < 8; ++q)
          er[q] = *(const bf16x8*)(eb + (long)(tb + q) * UU + lane * 8);
        float v[8];
#pragma unroll
        for (int q = 0; q < 8; ++q) {
          float d = 0.f;
#pragma unroll
          for (int j = 0; j < 8; ++j) d += hf[j] * (float)er[q][j];
          v[q] = d;
        }
        // multi-value butterfly: fold 8 dots while reducing (10 shfl total)
        {
          int up = lane & 1;
          float x[4], n4[4];
#pragma unroll
          for (int i = 0; i < 4; ++i) x[i] = up ? v[i] : v[i + 4];
#pragma unroll
          for (int i = 0; i < 4; ++i) {
            float r = __shfl_xor(x[i], 1);
            n4[i] = (up ? v[i + 4] : v[i]) + r;
          }
#pragma unroll
          for (int i = 0; i < 4; ++i) v[i] = n4[i];
        }
        {
          int up = lane & 2;
          float x0 = up ? v[0] : v[2], x1 = up ? v[1] : v[3];
          float r0 = __shfl_xor(x0, 2), r1 = __shfl_xor(x1, 2);
          float n0 = (up ? v[2] : v[0]) + r0;
          float n1 = (up ? v[3] : v[1]) + r1;
          v[0] = n0;
          v[1] = n1;
        }
        float d;
        {
          int up = lane & 4;
          float x = up ? v[0] : v[1];
          float r = __shfl_xor(x, 4);
          d = (up ? v[1] : v[0]) + r;
        }
        d += __shfl_xor(d, 8);
        d += __shfl_xor(d, 16);
        d += __shfl_xor(d, 32);
        float score = d * pw + pb;  // lane holds t = tb + bitrev3(lane&7)
        if (lane < 8) {
          static const int qperm[8] = {0, 4, 2, 6, 1, 5, 3, 7};
          sh.at.sc[tb + qperm[lane]] = score;
        }
        float cm = score;
        cm = fmaxf(cm, __shfl_xor(cm, 1));
        cm = fmaxf(cm, __shfl_xor(cm, 2));
        cm = fmaxf(cm, __shfl_xor(cm, 4));
        float mn = fmaxf(m, cm);
        float scale = __expf(m - mn);
        float w = __expf(score - mn);
        float wq[8];
        wq[0] = __shfl(w, 0);
        wq[1] = __shfl(w, 4);
        wq[2] = __shfl(w, 2);
        wq[3] = __shfl(w, 6);
        wq[4] = __shfl(w, 1);
        wq[5] = __shfl(w, 5);
        wq[6] = __shfl(w, 3);
        wq[7] = __shfl(w, 7);
        l = l * scale + (((wq[0] + wq[1]) + (wq[2] + wq[3])) +
                         ((wq[4] + wq[5]) + (wq[6] + wq[7])));
#pragma unroll
        for (int j = 0; j < 8; ++j) {
          float cj = ctx[j] * scale;
#pragma unroll
          for (int q = 0; q < 8; ++q) cj += wq[q] * (float)er[q][j];
          ctx[j] = cj;
        }
        m = mn;
      }

#pragma unroll
      for (int j = 0; j < 8; ++j) sh.at.ctxs[wave][lane * 8 + j] = ctx[j];
      if (lane == 0) {
        sh.at.mL[wave] = m;
        sh.at.lL[wave] = l;
      }
      __syncthreads();

      const float M = fmaxf(fmaxf(sh.at.mL[0], sh.at.mL[1]),
                            fmaxf(sh.at.mL[2], sh.at.mL[3]));
      const float s0 = __expf(sh.at.mL[0] - M), s1 = __expf(sh.at.mL[1] - M),
                  s2 = __expf(sh.at.mL[2] - M), s3 = __expf(sh.at.mL[3] - M);
      const float L = sh.at.lL[0] * s0 + sh.at.lL[1] * s1 + sh.at.lL[2] * s2 +
                      sh.at.lL[3] * s3;
      const float rinvL = 1.f / L;

      out[((long)b * TT + s) * TT + tid] = __expf(sh.at.sc[tid] - M) * rinvL;

      const int u0 = 2 * tid;
      float a0 = sh.at.ctxs[0][u0] * s0 + sh.at.ctxs[1][u0] * s1 +
                 sh.at.ctxs[2][u0] * s2 + sh.at.ctxs[3][u0] * s3;
      float a1 = sh.at.ctxs[0][u0 + 1] * s0 + sh.at.ctxs[1][u0 + 1] * s1 +
                 sh.at.ctxs[2][u0 + 1] * s2 + sh.at.ctxs[3][u0 + 1] * s3;
      bf16x2 o;
      o[0] = (bf16_t)(a0 * rinvL);
      o[1] = (bf16_t)(a1 * rinvL);
      *(bf16x2*)(xin + (long)b * UU + u0) = o;
    }
    gsync(syncw, ++nsync);
  }
}

// ---------------------------------------------------------------------------
extern "C" void kernel_launch(void* const* d_in, const int* in_sizes, int n_in,
                              void* d_out, int out_size, void* d_ws,
                              size_t ws_size, hipStream_t stream) {
  const float* inputs = (const float*)d_in[0];
  const float* score = (const float*)d_in[1];
  const float* enc_Wx = (const float*)d_in[2];
  const float* enc_Wh = (const float*)d_in[3];
  const float* enc_b = (const float*)d_in[4];
  const float* dec_Wx = (const float*)d_in[5];
  const float* dec_Wh = (const float*)d_in[6];
  const float* dec_b = (const float*)d_in[7];
  const float* ptr_w = (const float*)d_in[8];
  const float* ptr_b = (const float*)d_in[9];
  float* out = (float*)d_out;

  char* ws = (char*)d_ws;
  size_t off = 0;
  bf16_t* WencP = (bf16_t*)(ws + off); off += (size_t)2048 * 1024 * 2;
  bf16_t* WdecP = (bf16_t*)(ws + off); off += (size_t)2048 * 1024 * 2;
  bf16_t* enc_out = (bf16_t*)(ws + off); off += (size_t)BB * TT * UU * 2;
  bf16_t* Xbf = (bf16_t*)(ws + off); off += (size_t)TT * BB * UU * 2;
  bf16_t* hb0 = (bf16_t*)(ws + off); off += (size_t)BB * UU * 2;
  bf16_t* hb1 = (bf16_t*)(ws + off); off += (size_t)BB * UU * 2;
  bf16_t* xin = (bf16_t*)(ws + off); off += (size_t)BB * UU * 2;
  unsigned* syncw = (unsigned*)(ws + off); off += 2048;
  if (ws_size < off) return;  // insufficient scratch -> loud failure

  prep_weights<<<4096, 64, 0, stream>>>(enc_Wx, enc_Wh, WencP);
  prep_weights<<<4096, 64, 0, stream>>>(dec_Wx, dec_Wh, WdecP);
  prep_x<<<65536, 256, 0, stream>>>(inputs, score, Xbf);
  init_state<<<512, 256, 0, stream>>>(hb0, hb1, syncw);
  mean_kernel<<<512, 256, 0, stream>>>(Xbf, xin);

  pointer_net_persistent<<<256, 256, 0, stream>>>(
      Xbf, xin, WencP, WdecP, enc_b, dec_b, hb0, hb1, enc_out, ptr_w, ptr_b,
      out, syncw);
}

// Round 6
// 7041.700 us; speedup vs baseline: 2.5697x; 2.5697x over previous
//
#include <hip/hip_runtime.h>
#include <hip/hip_bf16.h>

#define BB 256
#define TT 256
#define FF 511
#define UU 512

typedef __bf16 bf16_t;
typedef __bf16 bf16x8 __attribute__((ext_vector_type(8)));
typedef __bf16 bf16x2 __attribute__((ext_vector_type(2)));
typedef float f32x4 __attribute__((ext_vector_type(4)));

__device__ __forceinline__ float fast_sigmoid(float x) {
  return 1.f / (1.f + __expf(-x));
}
__device__ __forceinline__ float fast_tanh(float x) {
  float a = fabsf(x);
  float t = 1.f - 2.f / (__expf(2.f * a) + 1.f);  // overflow-safe
  return copysignf(t, x);
}

// Coherent (cross-XCD) 16B load: two relaxed agent-scope u64 atomic loads
// (emit sc0|sc1 -> bypass L1/L2, read at L3 coherence point; no fence cost).
__device__ __forceinline__ bf16x8 coh_load16(const bf16_t* p) {
  union {
    unsigned long long u[2];
    bf16x8 v;
  } x;
  unsigned long long* q = (unsigned long long*)p;
  x.u[0] = __hip_atomic_load(q, __ATOMIC_RELAXED, __HIP_MEMORY_SCOPE_AGENT);
  x.u[1] = __hip_atomic_load(q + 1, __ATOMIC_RELAXED, __HIP_MEMORY_SCOPE_AGENT);
  return x.v;
}
// Coherent 4B store (two packed bf16).
__device__ __forceinline__ void coh_store4(bf16_t* p, float a, float b) {
  union {
    unsigned u;
    bf16x2 v;
  } pk;
  pk.v[0] = (bf16_t)a;
  pk.v[1] = (bf16_t)b;
  __hip_atomic_store((unsigned*)p, pk.u, __ATOMIC_RELAXED,
                     __HIP_MEMORY_SCOPE_AGENT);
}

// ---------------------------------------------------------------------------
// Weight prep -> fragment-major packed: Wp[frag][lane][8], frag = ntile*32+ko.
// ---------------------------------------------------------------------------
__global__ __launch_bounds__(64) void prep_weights(
    const float* __restrict__ Wx, const float* __restrict__ Wh,
    bf16_t* __restrict__ Wp) {
  int bid = blockIdx.x;  // ntile*32 + ko
  int ko = bid & 31;
  int ntile = bid >> 5;
  int lane = threadIdx.x;
  int n = ntile * 16 + (lane & 15);
  int kb = ko * 32 + (lane >> 4) * 8;
  const float* src = (kb < UU) ? Wx : Wh;
  int krel = (kb < UU) ? kb : kb - UU;
  bf16x8 v;
#pragma unroll
  for (int j = 0; j < 8; ++j) v[j] = (bf16_t)src[(long)(krel + j) * 2048 + n];
  *(bf16x8*)(Wp + (long)bid * 512 + lane * 8) = v;
}

// ---------------------------------------------------------------------------
__global__ __launch_bounds__(256) void prep_x(
    const float* __restrict__ inputs, const float* __restrict__ score,
    bf16_t* __restrict__ X) {
  int gid = blockIdx.x * 256 + threadIdx.x;
  int u = (gid & 255) * 2;
  int b = (gid >> 8) & 255;
  int t = gid >> 16;
  long ibase = (long)b * TT * FF + (long)t * FF;
  float v0 = inputs[ibase + u];
  float v1 = (u + 1 < FF) ? inputs[ibase + u + 1] : score[b];
  bf16x2 o;
  o[0] = (bf16_t)v0;
  o[1] = (bf16_t)v1;
  *(bf16x2*)(X + (long)t * BB * UU + b * UU + u) = o;
}

// Zero h ping-pong buffers and the barrier words (ws is poisoned 0xAA).
__global__ __launch_bounds__(256) void init_state(
    bf16_t* __restrict__ hb0, bf16_t* __restrict__ hb1,
    unsigned* __restrict__ syncw) {
  int idx = blockIdx.x * 256 + threadIdx.x;
  hb0[idx] = (bf16_t)0.f;
  hb1[idx] = (bf16_t)0.f;
  if (blockIdx.x == 0 && threadIdx.x < 512) syncw[threadIdx.x] = 0u;
}

__global__ __launch_bounds__(256) void mean_kernel(
    const bf16_t* __restrict__ X, bf16_t* __restrict__ xin) {
  int idx = blockIdx.x * 256 + threadIdx.x;  // b*512+u
  float acc = 0.f;
  for (int t = 0; t < TT; ++t) acc += (float)X[(long)t * BB * UU + idx];
  xin[idx] = (bf16_t)(acc * (1.0f / TT));
}

// ---------------------------------------------------------------------------
// Monotonic GROUP barrier, NO cache-maintenance fences. Group = blocks with
// the same (blockIdx & 7) -> XCD-aligned under round-robin dispatch (perf
// heuristic only; correctness comes from L3-coherent accesses).
// Release: __syncthreads drains vmcnt(0) before s_barrier -> all sc1 stores
// are at the L3 coherence point before lane 0 increments. Acquire: in-order
// issue after the spin-exit branch; data reads are sc1-bypass loads.
// ---------------------------------------------------------------------------
__device__ __forceinline__ void gsync(unsigned* syncw, unsigned n) {
  __syncthreads();
  if (threadIdx.x == 0) {
    const int g = blockIdx.x & 7;
    unsigned* cnt = syncw + g * 32;
    unsigned* gen = syncw + 256 + g * 32;
    unsigned old = __hip_atomic_fetch_add(cnt, 1u, __ATOMIC_RELAXED,
                                          __HIP_MEMORY_SCOPE_AGENT);
    if (old == n * 32u - 1u)  // last arrival of this group's round n
      __hip_atomic_store(gen, n, __ATOMIC_RELAXED, __HIP_MEMORY_SCOPE_AGENT);
    while (__hip_atomic_load(gen, __ATOMIC_RELAXED, __HIP_MEMORY_SCOPE_AGENT) <
           n) {
      __builtin_amdgcn_s_sleep(1);
    }
  }
  __syncthreads();
  asm volatile("" ::: "memory");
}

union ShU {
  float red[4][2][4][64][4];  // [kq][rt][gate][lane][reg] = 32 KiB
  struct {
    float sc[TT];
    float ctxs[4][UU];
    float mL[4];
    float lL[4];
  } at;  // aliased; phases separated by barriers
};

// ---------------------------------------------------------------------------
// One LSTM step. Wave = K-quarter, B-fragments in registers, A from global
// (h-half and, in decoder, x-half via coherent loads). LDS K-reduce.
// Epilogue: thread (wave w, lane) owns band row R = w*8+(lane>>3) and col
// pair 2*(lane&7) -> one 4B coherent store each for h and enc_out; c stays
// in registers for all 512 steps.
// ---------------------------------------------------------------------------
template <bool XCOH>
__device__ __forceinline__ void lstm_sub(
    const bf16x8 (&wreg)[4][8], const float (&bia)[2][4], const bf16_t* xsrc,
    const bf16_t* h_in, bf16_t* h_out, bf16_t* eslot,  // enc_out + t*UU or null
    float& c0, float& c1, ShU& sh, int mg, int js) {
  const int tid = threadIdx.x;
  const int wave = tid >> 6;  // = kq
  const int lane = tid & 63;
  const int quad = lane >> 4;
  const int l16 = lane & 15;

  f32x4 acc[2][4];
#pragma unroll
  for (int rt = 0; rt < 2; ++rt)
#pragma unroll
    for (int g = 0; g < 4; ++g) acc[rt][g] = (f32x4){0.f, 0.f, 0.f, 0.f};

  const bool xhalf = (wave < 2);
  const bf16_t* abase = xhalf ? xsrc : h_in;
  const int koff = (wave & 1) * 256;
  const long r0 = (long)(mg * 32 + l16) * UU;
  const long r1 = (long)(mg * 32 + 16 + l16) * UU;

#pragma unroll
  for (int kol = 0; kol < 8; ++kol) {
    const int kk = koff + kol * 32 + quad * 8;
    bf16x8 a0, a1;
    if (xhalf && !XCOH) {  // encoder x-half: read-only Xbf, keep cached
      a0 = *(const bf16x8*)(abase + r0 + kk);
      a1 = *(const bf16x8*)(abase + r1 + kk);
    } else {  // h (always) / decoder xin: cross-WG fresh -> coherent
      a0 = coh_load16(abase + r0 + kk);
      a1 = coh_load16(abase + r1 + kk);
    }
#pragma unroll
    for (int g = 0; g < 4; ++g) {
      acc[0][g] = __builtin_amdgcn_mfma_f32_16x16x32_bf16(a0, wreg[g][kol],
                                                          acc[0][g], 0, 0, 0);
      acc[1][g] = __builtin_amdgcn_mfma_f32_16x16x32_bf16(a1, wreg[g][kol],
                                                          acc[1][g], 0, 0, 0);
    }
  }

#pragma unroll
  for (int rt = 0; rt < 2; ++rt)
#pragma unroll
    for (int g = 0; g < 4; ++g)
      *(f32x4*)&sh.red[wave][rt][g][lane][0] = acc[rt][g];
  __syncthreads();

  // Epilogue: R = wave*8 + (lane>>3) in [0,32); cols 2cp, 2cp+1 (cp=lane&7).
  const int R = wave * 8 + (lane >> 3);
  const int cp = lane & 7;
  const int rt = R >> 4;
  const int row16 = R & 15;
  const int q16 = row16 >> 2;
  const int rr = row16 & 3;
  float hv[2];
#pragma unroll
  for (int cc = 0; cc < 2; ++cc) {
    const int col = 2 * cp + cc;
    float z[4];
#pragma unroll
    for (int g = 0; g < 4; ++g) {
      z[g] = bia[cc][g];
#pragma unroll
      for (int kq = 0; kq < 4; ++kq)
        z[g] += sh.red[kq][rt][g][q16 * 16 + col][rr];
    }
    float ig = fast_sigmoid(z[0]);
    float fg = fast_sigmoid(z[1]);
    float gg = fast_tanh(z[2]);
    float og = fast_sigmoid(z[3]);
    float& cref = cc ? c1 : c0;
    float cn = fg * cref + ig * gg;
    hv[cc] = og * fast_tanh(cn);
    cref = cn;
  }
  const int brow = mg * 32 + R;
  const long uoff = (long)brow * UU + js * 16 + 2 * cp;
  coh_store4(h_out + uoff, hv[0], hv[1]);
  if (eslot)
    coh_store4(eslot + (long)brow * TT * UU + js * 16 + 2 * cp, hv[0], hv[1]);
}

// ---------------------------------------------------------------------------
// Persistent kernel: 256 WGs x 256 threads, regular launch, group barriers.
// mg = blockIdx&7 (batch band, XCD-aligned), js = blockIdx>>3 (gate-col tile).
// ---------------------------------------------------------------------------
__global__ __launch_bounds__(256, 1) void pointer_net_persistent(
    const bf16_t* __restrict__ Xbf, bf16_t* __restrict__ xin,
    const bf16_t* __restrict__ WencP, const bf16_t* __restrict__ WdecP,
    const float* __restrict__ enc_b, const float* __restrict__ dec_b,
    bf16_t* __restrict__ h0, bf16_t* __restrict__ h1,
    bf16_t* __restrict__ enc_out, const float* __restrict__ ptr_w,
    const float* __restrict__ ptr_b, float* __restrict__ out,
    unsigned* __restrict__ syncw) {
  __shared__ ShU sh;
  const int tid = threadIdx.x;
  const int wave = tid >> 6;
  const int lane = tid & 63;
  const int mg = blockIdx.x & 7;   // batch band
  const int js = blockIdx.x >> 3;  // gate-col tile
  const int b_att = mg * 32 + js;  // attention batch row (inside own band)

  const float pw = *ptr_w, pb = *ptr_b;

  bf16x8 wreg[4][8];
  float bia[2][4];
#pragma unroll
  for (int g = 0; g < 4; ++g) {
#pragma unroll
    for (int kol = 0; kol < 8; ++kol) {
      long frag = (long)(g * 32 + js) * 32 + wave * 8 + kol;
      wreg[g][kol] = *(const bf16x8*)(WencP + frag * 512 + lane * 8);
    }
#pragma unroll
    for (int cc = 0; cc < 2; ++cc)
      bia[cc][g] = enc_b[g * UU + js * 16 + 2 * (lane & 7) + cc];
  }

  float c0 = 0.f, c1 = 0.f;
  bf16_t* hp[2] = {h0, h1};
  int p = 0;
  unsigned nsync = 0;

  // -------- Encoder: 256 steps --------
  for (int t = 0; t < TT; ++t) {
    lstm_sub<false>(wreg, bia, Xbf + (long)t * BB * UU, hp[p], hp[p ^ 1],
                    enc_out + (long)t * UU, c0, c1, sh, mg, js);
    p ^= 1;
    gsync(syncw, ++nsync);
  }

  // -------- Switch to decoder weights --------
#pragma unroll
  for (int g = 0; g < 4; ++g) {
#pragma unroll
    for (int kol = 0; kol < 8; ++kol) {
      long frag = (long)(g * 32 + js) * 32 + wave * 8 + kol;
      wreg[g][kol] = *(const bf16x8*)(WdecP + frag * 512 + lane * 8);
    }
#pragma unroll
    for (int cc = 0; cc < 2; ++cc)
      bia[cc][g] = dec_b[g * UU + js * 16 + 2 * (lane & 7) + cc];
  }

  // -------- Decoder: 256 steps of (LSTM, attention) --------
  for (int s = 0; s < TT; ++s) {
    lstm_sub<true>(wreg, bia, xin, hp[p], hp[p ^ 1], nullptr, c0, c1, sh, mg,
                   js);
    p ^= 1;
    gsync(syncw, ++nsync);

    // ---- Attention (WG = batch row b_att), online softmax ----
    {
      const int b = b_att;
      bf16x8 hvv = coh_load16(hp[p] + (long)b * UU + lane * 8);
      float hf[8];
#pragma unroll
      for (int j = 0; j < 8; ++j) hf[j] = (float)hvv[j];

      const bf16_t* eb = enc_out + (long)b * TT * UU;  // read-only: cached
      float m = -1e30f, l = 0.f;
      float ctx[8];
#pragma unroll
      for (int j = 0; j < 8; ++j) ctx[j] = 0.f;

      for (int ch = 0; ch < 8; ++ch) {
        const int tb = wave * 64 + ch * 8;
        bf16x8 er[8];
#pragma unroll
        for (int q = 0; q < 8; ++q)
          er[q] = *(const bf16x8*)(eb + (long)(tb + q) * UU + lane * 8);
        float v[8];
#pragma unroll
        for (int q = 0; q < 8; ++q) {
          float d = 0.f;
#pragma unroll
          for (int j = 0; j < 8; ++j) d += hf[j] * (float)er[q][j];
          v[q] = d;
        }
        // multi-value butterfly: fold 8 dots while reducing (10 shfl total)
        {
          int up = lane & 1;
          float x[4], n4[4];
#pragma unroll
          for (int i = 0; i < 4; ++i) x[i] = up ? v[i] : v[i + 4];
#pragma unroll
          for (int i = 0; i < 4; ++i) {
            float r = __shfl_xor(x[i], 1);
            n4[i] = (up ? v[i + 4] : v[i]) + r;
          }
#pragma unroll
          for (int i = 0; i < 4; ++i) v[i] = n4[i];
        }
        {
          int up = lane & 2;
          float x0 = up ? v[0] : v[2], x1 = up ? v[1] : v[3];
          float r0 = __shfl_xor(x0, 2), r1 = __shfl_xor(x1, 2);
          float n0 = (up ? v[2] : v[0]) + r0;
          float n1 = (up ? v[3] : v[1]) + r1;
          v[0] = n0;
          v[1] = n1;
        }
        float d;
        {
          int up = lane & 4;
          float x = up ? v[0] : v[1];
          float r = __shfl_xor(x, 4);
          d = (up ? v[1] : v[0]) + r;
        }
        d += __shfl_xor(d, 8);
        d += __shfl_xor(d, 16);
        d += __shfl_xor(d, 32);
        float score = d * pw + pb;  // lane holds t = tb + bitrev3(lane&7)
        if (lane < 8) {
          static const int qperm[8] = {0, 4, 2, 6, 1, 5, 3, 7};
          sh.at.sc[tb + qperm[lane]] = score;
        }
        float cm = score;
        cm = fmaxf(cm, __shfl_xor(cm, 1));
        cm = fmaxf(cm, __shfl_xor(cm, 2));
        cm = fmaxf(cm, __shfl_xor(cm, 4));
        float mn = fmaxf(m, cm);
        float scale = __expf(m - mn);
        float w = __expf(score - mn);
        float wq[8];
        wq[0] = __shfl(w, 0);
        wq[1] = __shfl(w, 4);
        wq[2] = __shfl(w, 2);
        wq[3] = __shfl(w, 6);
        wq[4] = __shfl(w, 1);
        wq[5] = __shfl(w, 5);
        wq[6] = __shfl(w, 3);
        wq[7] = __shfl(w, 7);
        l = l * scale + (((wq[0] + wq[1]) + (wq[2] + wq[3])) +
                         ((wq[4] + wq[5]) + (wq[6] + wq[7])));
#pragma unroll
        for (int j = 0; j < 8; ++j) {
          float cj = ctx[j] * scale;
#pragma unroll
          for (int q = 0; q < 8; ++q) cj += wq[q] * (float)er[q][j];
          ctx[j] = cj;
        }
        m = mn;
      }

      // b128 LDS publishes (conflict-light; was 8-way-conflicted scalars)
      *(f32x4*)&sh.at.ctxs[wave][lane * 8] =
          (f32x4){ctx[0], ctx[1], ctx[2], ctx[3]};
      *(f32x4*)&sh.at.ctxs[wave][lane * 8 + 4] =
          (f32x4){ctx[4], ctx[5], ctx[6], ctx[7]};
      if (lane == 0) {
        sh.at.mL[wave] = m;
        sh.at.lL[wave] = l;
      }
      __syncthreads();

      const float M = fmaxf(fmaxf(sh.at.mL[0], sh.at.mL[1]),
                            fmaxf(sh.at.mL[2], sh.at.mL[3]));
      const float s0 = __expf(sh.at.mL[0] - M), s1 = __expf(sh.at.mL[1] - M),
                  s2 = __expf(sh.at.mL[2] - M), s3 = __expf(sh.at.mL[3] - M);
      const float L = sh.at.lL[0] * s0 + sh.at.lL[1] * s1 + sh.at.lL[2] * s2 +
                      sh.at.lL[3] * s3;
      const float rinvL = 1.f / L;

      out[((long)b * TT + s) * TT + tid] = __expf(sh.at.sc[tid] - M) * rinvL;

      const int u0 = 2 * tid;
      float a0 = sh.at.ctxs[0][u0] * s0 + sh.at.ctxs[1][u0] * s1 +
                 sh.at.ctxs[2][u0] * s2 + sh.at.ctxs[3][u0] * s3;
      float a1 = sh.at.ctxs[0][u0 + 1] * s0 + sh.at.ctxs[1][u0 + 1] * s1 +
                 sh.at.ctxs[2][u0 + 1] * s2 + sh.at.ctxs[3][u0 + 1] * s3;
      coh_store4(xin + (long)b * UU + u0, a0 * rinvL, a1 * rinvL);
    }
    gsync(syncw, ++nsync);
  }
}

// ---------------------------------------------------------------------------
extern "C" void kernel_launch(void* const* d_in, const int* in_sizes, int n_in,
                              void* d_out, int out_size, void* d_ws,
                              size_t ws_size, hipStream_t stream) {
  const float* inputs = (const float*)d_in[0];
  const float* score = (const float*)d_in[1];
  const float* enc_Wx = (const float*)d_in[2];
  const float* enc_Wh = (const float*)d_in[3];
  const float* enc_b = (const float*)d_in[4];
  const float* dec_Wx = (const float*)d_in[5];
  const float* dec_Wh = (const float*)d_in[6];
  const float* dec_b = (const float*)d_in[7];
  const float* ptr_w = (const float*)d_in[8];
  const float* ptr_b = (const float*)d_in[9];
  float* out = (float*)d_out;

  char* ws = (char*)d_ws;
  size_t off = 0;
  bf16_t* WencP = (bf16_t*)(ws + off); off += (size_t)2048 * 1024 * 2;
  bf16_t* WdecP = (bf16_t*)(ws + off); off += (size_t)2048 * 1024 * 2;
  bf16_t* enc_out = (bf16_t*)(ws + off); off += (size_t)BB * TT * UU * 2;
  bf16_t* Xbf = (bf16_t*)(ws + off); off += (size_t)TT * BB * UU * 2;
  bf16_t* hb0 = (bf16_t*)(ws + off); off += (size_t)BB * UU * 2;
  bf16_t* hb1 = (bf16_t*)(ws + off); off += (size_t)BB * UU * 2;
  bf16_t* xin = (bf16_t*)(ws + off); off += (size_t)BB * UU * 2;
  unsigned* syncw = (unsigned*)(ws + off); off += 2048;
  if (ws_size < off) return;  // insufficient scratch -> loud failure

  prep_weights<<<4096, 64, 0, stream>>>(enc_Wx, enc_Wh, WencP);
  prep_weights<<<4096, 64, 0, stream>>>(dec_Wx, dec_Wh, WdecP);
  prep_x<<<65536, 256, 0, stream>>>(inputs, score, Xbf);
  init_state<<<512, 256, 0, stream>>>(hb0, hb1, syncw);
  mean_kernel<<<512, 256, 0, stream>>>(Xbf, xin);

  pointer_net_persistent<<<256, 256, 0, stream>>>(
      Xbf, xin, WencP, WdecP, enc_b, dec_b, hb0, hb1, enc_out, ptr_w, ptr_b,
      out, syncw);
}